// Round 13
// baseline (1884.423 us; speedup 1.0000x reference)
//
#include <hip/hip_runtime.h>

// GraphNormalization on MI355X — R13: register-resident chunks, no re-read.
//
// Model (R0-R12): the binding constraint is total VMEM-path traffic
// (loads incl. cache hits + stores) at ~6.3 TB/s chip-wide:
//   R8 = (1.03 HBM-R + 1.03 L3-R + 1.03 W) GB / 489us = 6.30 TB/s = m13 copy
//   ceiling; fill = 1 op/elem = 6.5; copy = 2 ops/elem = 3.15+3.15.
// Phase overlap cannot help (ops conserved) -> R7/R9/R10/R12 all failed.
// R13 removes the 1.03 GB re-read: chunk lives in VGPRs between passes.
//   grid = (1024 segs x 5 chunks) x 2 tensors; 256 thr; 32 f4/thread cache.
//   stats: block partial -> d_ws slot -> atomic counter -> finisher reduces
//   (fixed order, deterministic) -> release flag -> peers acquire ->
//   transform from registers + NT store. Traffic 2.06 GB -> ~330us floor.

static constexpr int   RV       = 32;           // float4 per thread (128 VGPR)
static constexpr int   CHUNK_F4 = RV * 256;     // 8192 f4 = 128 KB per block
static constexpr int   CPS      = 5;            // chunks per segment (<=1280 rows)
static constexpr float EPS      = 1e-5f;

typedef float vfloat4 __attribute__((ext_vector_type(4)));

__device__ __forceinline__ void nt_store4(float4* p, const float4& v) {
    vfloat4 w = { v.x, v.y, v.z, v.w };
    __builtin_nontemporal_store(w, reinterpret_cast<vfloat4*>(p));
}

__device__ __forceinline__ void acc4(float4& s, float4& q, const float4& v) {
    s.x += v.x; s.y += v.y; s.z += v.z; s.w += v.w;
    q.x += v.x * v.x; q.y += v.y * v.y;
    q.z += v.z * v.z; q.w += v.w * v.w;
}

__device__ __forceinline__ float4 affine4(const float4& v, const float4& A,
                                          const float4& Bc) {
    float4 o;
    o.x = v.x * A.x + Bc.x; o.y = v.y * A.y + Bc.y;
    o.z = v.z * A.z + Bc.z; o.w = v.w * A.w + Bc.w;
    return o;
}

__global__ __launch_bounds__(256) void seg_norm_reg(
    const float4* __restrict__ xn, const float4* __restrict__ xe,
    const float*  __restrict__ gn, const float*  __restrict__ bn,
    const float*  __restrict__ ge, const float*  __restrict__ be,
    const int*    __restrict__ sn, const int*    __restrict__ se,
    float4* __restrict__ on, float4* __restrict__ oe,
    int* __restrict__ wsCnt, int* __restrict__ wsFlag,
    float4* __restrict__ wsA, float4* __restrict__ wsB,
    float4* __restrict__ wsP, int N)
{
    __shared__ float4 pS[4][32], pQ[4][32];
    __shared__ float4 sA[32], sB[32];
    __shared__ int    sm[4];

    const int  bx     = (int)blockIdx.x;
    const int  segid  = bx / CPS;
    const int  c      = bx % CPS;
    const bool is_edge = (blockIdx.y != 0);
    const int  slot   = (is_edge ? 1024 : 0) + segid;
    const int  tid    = (int)threadIdx.x;
    const int  w      = tid >> 6;
    const int  lane   = tid & 63;
    const int  dg     = tid & 31;

    const float4* __restrict__ x    = is_edge ? xe : xn;
    float4*       __restrict__ outp = is_edge ? oe : on;
    const float*  __restrict__ gam  = is_edge ? ge : gn;
    const float*  __restrict__ bet  = is_edge ? be : bn;
    const int*    __restrict__ seg  = is_edge ? se : sn;

    if (tid < 2) {
        const int target = segid + tid;
        int lo = 0, hi = N;
        while (lo < hi) {
            int mid = (lo + hi) >> 1;
            if (seg[mid] < target) lo = mid + 1; else hi = mid;
        }
        sm[tid] = lo;
    }
    __syncthreads();
    const int start = sm[0], end = sm[1];
    const int cnt   = end - start;
    if (cnt <= 0) return;

    const int f4cnt = cnt * 32;                       // D4 = 32
    const int nb    = min((f4cnt + CHUNK_F4 - 1) / CHUNK_F4, CPS);
    if (c >= nb) return;
    const size_t fb   = (size_t)start * 32;
    const int    coff = c * CHUNK_F4;
    const int    rem  = f4cnt - coff;                 // > 0

    // ---- load chunk into registers (statically indexed) + accumulate ----
    const float4* src_ = x + fb + coff;
    float4 cache[RV];
    #pragma unroll
    for (int k = 0; k < RV; ++k) {
        const int idx = k * 256 + tid;
        cache[k] = (idx < rem) ? src_[idx] : make_float4(0.f, 0.f, 0.f, 0.f);
    }
    float4 s = make_float4(0.f, 0.f, 0.f, 0.f);
    float4 q = make_float4(0.f, 0.f, 0.f, 0.f);
    #pragma unroll
    for (int k = 0; k < RV; ++k) acc4(s, q, cache[k]);
    // overflow rows beyond CPS chunks (P ~ 1e-19): stream-in for stats
    if (c == CPS - 1)
        for (int j = CPS * CHUNK_F4 + tid; j < f4cnt; j += 256)
            acc4(s, q, x[fb + j]);

    // ---- block-level fold: lanes l/l+32 share a dim-group ----
    s.x += __shfl_down(s.x, 32); s.y += __shfl_down(s.y, 32);
    s.z += __shfl_down(s.z, 32); s.w += __shfl_down(s.w, 32);
    q.x += __shfl_down(q.x, 32); q.y += __shfl_down(q.y, 32);
    q.z += __shfl_down(q.z, 32); q.w += __shfl_down(q.w, 32);
    if (lane < 32) { pS[w][lane] = s; pQ[w][lane] = q; }
    __syncthreads();

    // ---- publish partial to ws slot ----
    const size_t pbase = ((size_t)slot * CPS + c) * 64;
    if (tid < 32) {
        float4 S = pS[0][tid], Q = pQ[0][tid];
        #pragma unroll
        for (int k = 1; k < 4; ++k) {
            const float4 a = pS[k][tid], cc = pQ[k][tid];
            S.x += a.x; S.y += a.y; S.z += a.z; S.w += a.w;
            Q.x += cc.x; Q.y += cc.y; Q.z += cc.z; Q.w += cc.w;
        }
        wsP[pbase + tid]      = S;
        wsP[pbase + 32 + tid] = Q;
    }
    __syncthreads();
    if (tid == 0) {
        __threadfence();
        const int prev = __hip_atomic_fetch_add(&wsCnt[slot], 1,
                             __ATOMIC_ACQ_REL, __HIP_MEMORY_SCOPE_AGENT);
        sm[2] = (prev == nb - 1);
    }
    __syncthreads();

    if (sm[2]) {   // ---- finisher: reduce slots (fixed order), fold gamma/beta
        if (tid < 32) {
            float4 S = make_float4(0.f, 0.f, 0.f, 0.f);
            float4 Q = make_float4(0.f, 0.f, 0.f, 0.f);
            for (int cc = 0; cc < nb; ++cc) {
                const size_t pb = ((size_t)slot * CPS + cc) * 64;
                const float4 a = wsP[pb + tid], b2 = wsP[pb + 32 + tid];
                S.x += a.x; S.y += a.y; S.z += a.z; S.w += a.w;
                Q.x += b2.x; Q.y += b2.y; Q.z += b2.z; Q.w += b2.w;
            }
            const float rc = 1.0f / (float)cnt;
            float4 m, iv;
            m.x = S.x * rc; m.y = S.y * rc; m.z = S.z * rc; m.w = S.w * rc;
            iv.x = 1.0f / (sqrtf(fmaxf(Q.x * rc - m.x * m.x, 0.f)) + EPS);
            iv.y = 1.0f / (sqrtf(fmaxf(Q.y * rc - m.y * m.y, 0.f)) + EPS);
            iv.z = 1.0f / (sqrtf(fmaxf(Q.z * rc - m.z * m.z, 0.f)) + EPS);
            iv.w = 1.0f / (sqrtf(fmaxf(Q.w * rc - m.w * m.w, 0.f)) + EPS);
            if (cnt <= 1) {   // pass-through: out = x*gamma + beta
                m  = make_float4(0.f, 0.f, 0.f, 0.f);
                iv = make_float4(1.f, 1.f, 1.f, 1.f);
            }
            const float4 g4 = ((const float4*)gam)[tid];
            const float4 b4 = ((const float4*)bet)[tid];
            float4 A, Bc;
            A.x = iv.x * g4.x; A.y = iv.y * g4.y;
            A.z = iv.z * g4.z; A.w = iv.w * g4.w;
            Bc.x = b4.x - m.x * A.x; Bc.y = b4.y - m.y * A.y;
            Bc.z = b4.z - m.z * A.z; Bc.w = b4.w - m.w * A.w;
            wsA[(size_t)slot * 32 + tid] = A;
            wsB[(size_t)slot * 32 + tid] = Bc;
        }
        __syncthreads();
        if (tid == 0) {
            __threadfence();
            __hip_atomic_store(&wsFlag[slot], 1,
                               __ATOMIC_RELEASE, __HIP_MEMORY_SCOPE_AGENT);
        }
    }

    // ---- wait for stats, broadcast, transform from registers, write ----
    if (tid == 0) {
        while (!__hip_atomic_load(&wsFlag[slot], __ATOMIC_ACQUIRE,
                                  __HIP_MEMORY_SCOPE_AGENT))
            __builtin_amdgcn_s_sleep(8);
    }
    __syncthreads();
    if (tid < 32) {
        sA[tid] = wsA[(size_t)slot * 32 + tid];
        sB[tid] = wsB[(size_t)slot * 32 + tid];
    }
    __syncthreads();
    const float4 A  = sA[dg];
    const float4 Bc = sB[dg];

    float4* dst_ = outp + fb + coff;
    #pragma unroll
    for (int k = 0; k < RV; ++k) {
        const int idx = k * 256 + tid;
        if (idx < rem) nt_store4(&dst_[idx], affine4(cache[k], A, Bc));
    }
    if (c == CPS - 1)
        for (int j = CPS * CHUNK_F4 + tid; j < f4cnt; j += 256)
            nt_store4(&outp[fb + j], affine4(x[fb + j], A, Bc));
}

// ---------- fallback (ws too small): simple self-contained 2-pass ----------
__global__ __launch_bounds__(256) void seg_norm_simple(
    const float4* __restrict__ xn, const float4* __restrict__ xe,
    const float*  __restrict__ gn, const float*  __restrict__ bn,
    const float*  __restrict__ ge, const float*  __restrict__ be,
    const int*    __restrict__ sn, const int*    __restrict__ se,
    float4* __restrict__ on, float4* __restrict__ oe, int N)
{
    __shared__ float4 pS[4][32], pQ[4][32];
    __shared__ int sm[2];
    const bool is_edge = (blockIdx.y != 0);
    const float4* x = is_edge ? xe : xn;
    const float* gam = is_edge ? ge : gn;
    const float* bet = is_edge ? be : bn;
    const int* seg = is_edge ? se : sn;
    float4* out = is_edge ? oe : on;
    const int b = (int)blockIdx.x, tid = (int)threadIdx.x;
    const int w = tid >> 6, lane = tid & 63, dg = tid & 31;
    if (tid < 2) {
        const int target = b + tid; int lo = 0, hi = N;
        while (lo < hi) { int mid = (lo + hi) >> 1;
            if (seg[mid] < target) lo = mid + 1; else hi = mid; }
        sm[tid] = lo;
    }
    __syncthreads();
    const int start = sm[0], end = sm[1], cnt = end - start;
    if (cnt <= 0) return;
    const size_t fb = (size_t)start * 32; const int fc = cnt * 32;
    float4 s = make_float4(0,0,0,0), q = make_float4(0,0,0,0);
    for (int j = tid; j < fc; j += 256) acc4(s, q, x[fb + j]);
    s.x += __shfl_down(s.x, 32); s.y += __shfl_down(s.y, 32);
    s.z += __shfl_down(s.z, 32); s.w += __shfl_down(s.w, 32);
    q.x += __shfl_down(q.x, 32); q.y += __shfl_down(q.y, 32);
    q.z += __shfl_down(q.z, 32); q.w += __shfl_down(q.w, 32);
    if (lane < 32) { pS[w][lane] = s; pQ[w][lane] = q; }
    __syncthreads();
    if (tid < 32) {
        float4 S = pS[0][tid], Q = pQ[0][tid];
        #pragma unroll
        for (int k = 1; k < 4; ++k) {
            const float4 a = pS[k][tid], c2 = pQ[k][tid];
            S.x += a.x; S.y += a.y; S.z += a.z; S.w += a.w;
            Q.x += c2.x; Q.y += c2.y; Q.z += c2.z; Q.w += c2.w;
        }
        const float rc = 1.0f / (float)cnt;
        float4 m, iv;
        m.x = S.x * rc; m.y = S.y * rc; m.z = S.z * rc; m.w = S.w * rc;
        iv.x = 1.0f / (sqrtf(fmaxf(Q.x * rc - m.x * m.x, 0.f)) + EPS);
        iv.y = 1.0f / (sqrtf(fmaxf(Q.y * rc - m.y * m.y, 0.f)) + EPS);
        iv.z = 1.0f / (sqrtf(fmaxf(Q.z * rc - m.z * m.z, 0.f)) + EPS);
        iv.w = 1.0f / (sqrtf(fmaxf(Q.w * rc - m.w * m.w, 0.f)) + EPS);
        if (cnt <= 1) { m = make_float4(0,0,0,0); iv = make_float4(1,1,1,1); }
        const float4 g4 = ((const float4*)gam)[tid];
        const float4 b4 = ((const float4*)bet)[tid];
        float4 A, Bc;
        A.x = iv.x*g4.x; A.y = iv.y*g4.y; A.z = iv.z*g4.z; A.w = iv.w*g4.w;
        Bc.x = b4.x - m.x*A.x; Bc.y = b4.y - m.y*A.y;
        Bc.z = b4.z - m.z*A.z; Bc.w = b4.w - m.w*A.w;
        pS[0][tid] = A; pQ[0][tid] = Bc;
    }
    __syncthreads();
    const float4 A = pS[0][dg], Bc = pQ[0][dg];
    for (int j = tid; j < fc; j += 256)
        nt_store4(&out[fb + j], affine4(x[fb + j], A, Bc));
}

extern "C" void kernel_launch(void* const* d_in, const int* in_sizes, int n_in,
                              void* d_out, int out_size, void* d_ws, size_t ws_size,
                              hipStream_t stream) {
    const float* node_feat  = (const float*)d_in[0];
    const float* edge_feat  = (const float*)d_in[1];
    const float* node_gamma = (const float*)d_in[2];
    const float* node_beta  = (const float*)d_in[3];
    const float* edge_gamma = (const float*)d_in[4];
    const float* edge_beta  = (const float*)d_in[5];
    const int*   node_seg   = (const int*)d_in[6];
    const int*   edge_seg   = (const int*)d_in[7];

    const int D = in_sizes[2];        // 128
    const int N = in_sizes[0] / D;    // 1,000,000
    const int B = 1024;               // num_graphs (fixed by setup_inputs)

    float* out_node = (float*)d_out;
    float* out_edge = out_node + (size_t)N * (size_t)D;

    // ws layout: cnt[2048] flag[2048] | A[2048*32 f4] | B[...] | P[2048*5*64 f4]
    const size_t offFlag = 2048 * sizeof(int);
    const size_t offA    = 16384;                       // 16 KB aligned
    const size_t offB    = offA + (size_t)2048 * 32 * 16;
    const size_t offP    = offB + (size_t)2048 * 32 * 16;
    const size_t need    = offP + (size_t)2048 * CPS * 64 * 16;

    if (ws_size >= need) {
        hipMemsetAsync(d_ws, 0, offA, stream);          // counters + flags
        seg_norm_reg<<<dim3((unsigned)(B * CPS), 2), 256, 0, stream>>>(
            (const float4*)node_feat, (const float4*)edge_feat,
            node_gamma, node_beta, edge_gamma, edge_beta,
            node_seg, edge_seg,
            (float4*)out_node, (float4*)out_edge,
            (int*)d_ws, (int*)((char*)d_ws + offFlag),
            (float4*)((char*)d_ws + offA), (float4*)((char*)d_ws + offB),
            (float4*)((char*)d_ws + offP), N);
    } else {
        seg_norm_simple<<<dim3((unsigned)B, 2), 256, 0, stream>>>(
            (const float4*)node_feat, (const float4*)edge_feat,
            node_gamma, node_beta, edge_gamma, edge_beta,
            node_seg, edge_seg,
            (float4*)out_node, (float4*)out_edge, N);
    }
}

// Round 14
// 686.294 us; speedup vs baseline: 2.7458x; 2.7458x over previous
//
#include <hip/hip_runtime.h>

// GraphNormalization on MI355X — R14: true register-resident, no cross-block sync.
//
// Model: binding constraint is total VMEM-path traffic (~6.3 TB/s: R8 =
// 3.08GB/489us = 6.30). Removing the pass-B re-read -> 2.06GB -> ~330-400us.
// R13 failed on mechanics (VGPR_Count=96 proved the reg-cache spilled;
// cross-block spin serialized). R14:
//   * __launch_bounds__(256,1): 1 wave/SIMD -> 512-VGPR budget, RV=88 f4
//     cache (352 VGPR) genuinely register-resident (m24: no spill to 450).
//   * one block = node seg b + edge seg b; only __syncthreads.
//   * mid phase interleaves store(node)/load(edge) PER K reusing the same
//     register (stores capture data at issue) -> 1.03R + 1.03W concurrent
//     in one wave with a single trailing waitcnt.
// Tails beyond the cache stream twice (L2-hot). Traffic ~2.3GB.

static constexpr int   RV  = 88;     // float4 cached per thread
static constexpr int   CAP = RV * 256;  // f4 per block-cache (=704 rows)
static constexpr float EPS = 1e-5f;

typedef float vfloat4 __attribute__((ext_vector_type(4)));

__device__ __forceinline__ void nt_store4(float4* p, const float4& v) {
    vfloat4 w = { v.x, v.y, v.z, v.w };
    __builtin_nontemporal_store(w, reinterpret_cast<vfloat4*>(p));
}

__device__ __forceinline__ void acc4(float4& s, float4& q, const float4& v) {
    s.x += v.x; s.y += v.y; s.z += v.z; s.w += v.w;
    q.x += v.x * v.x; q.y += v.y * v.y;
    q.z += v.z * v.z; q.w += v.w * v.w;
}

__device__ __forceinline__ float4 affine4(const float4& v, const float4& A,
                                          const float4& Bc) {
    float4 o;
    o.x = v.x * A.x + Bc.x; o.y = v.y * A.y + Bc.y;
    o.z = v.z * A.z + Bc.z; o.w = v.w * A.w + Bc.w;
    return o;
}

__global__ __launch_bounds__(256, 1) void seg_norm_rr(
    const float4* __restrict__ xn, const float4* __restrict__ xe,
    const float*  __restrict__ gn, const float*  __restrict__ bn,
    const float*  __restrict__ ge, const float*  __restrict__ be,
    const int*    __restrict__ sn, const int*    __restrict__ se,
    float4* __restrict__ on, float4* __restrict__ oe,
    int N)
{
    __shared__ float4 pS[4][32], pQ[4][32];
    __shared__ int    sm[4];

    const int b    = (int)blockIdx.x;
    const int tid  = (int)threadIdx.x;
    const int w    = tid >> 6;
    const int lane = tid & 63;
    const int dg   = tid & 31;

    if (tid < 4) {
        const int* sg    = (tid < 2) ? sn : se;
        const int target = b + (tid & 1);
        int lo = 0, hi = N;
        while (lo < hi) {
            int mid = (lo + hi) >> 1;
            if (sg[mid] < target) lo = mid + 1; else hi = mid;
        }
        sm[tid] = lo;
    }
    __syncthreads();
    const int st0 = sm[0], cnt0 = sm[1] - sm[0];
    const int st1 = sm[2], cnt1 = sm[3] - sm[2];
    const size_t fb0 = (size_t)st0 * 32;  const int fc0 = cnt0 * 32;
    const size_t fb1 = (size_t)st1 * 32;  const int fc1 = cnt1 * 32;

    // fold: in-wave 32-shuffle + cross-wave LDS; returns A/Bc via pS[0]/pQ[0]
    auto fold = [&](float4 s, float4 q, int cnt,
                    const float* gam, const float* bet,
                    float4& A_out, float4& Bc_out) {
        s.x += __shfl_down(s.x, 32); s.y += __shfl_down(s.y, 32);
        s.z += __shfl_down(s.z, 32); s.w += __shfl_down(s.w, 32);
        q.x += __shfl_down(q.x, 32); q.y += __shfl_down(q.y, 32);
        q.z += __shfl_down(q.z, 32); q.w += __shfl_down(q.w, 32);
        __syncthreads();               // LDS free (prior readers done)
        if (lane < 32) { pS[w][lane] = s; pQ[w][lane] = q; }
        __syncthreads();
        if (tid < 32) {
            float4 S = pS[0][tid], Q = pQ[0][tid];
            #pragma unroll
            for (int k = 1; k < 4; ++k) {
                const float4 a = pS[k][tid], c = pQ[k][tid];
                S.x += a.x; S.y += a.y; S.z += a.z; S.w += a.w;
                Q.x += c.x; Q.y += c.y; Q.z += c.z; Q.w += c.w;
            }
            const float rc = 1.0f / (float)max(cnt, 1);
            float4 m, iv;
            m.x = S.x * rc; m.y = S.y * rc; m.z = S.z * rc; m.w = S.w * rc;
            iv.x = 1.0f / (sqrtf(fmaxf(Q.x * rc - m.x * m.x, 0.f)) + EPS);
            iv.y = 1.0f / (sqrtf(fmaxf(Q.y * rc - m.y * m.y, 0.f)) + EPS);
            iv.z = 1.0f / (sqrtf(fmaxf(Q.z * rc - m.z * m.z, 0.f)) + EPS);
            iv.w = 1.0f / (sqrtf(fmaxf(Q.w * rc - m.w * m.w, 0.f)) + EPS);
            if (cnt <= 1) {            // pass-through: out = x*gamma + beta
                m  = make_float4(0.f, 0.f, 0.f, 0.f);
                iv = make_float4(1.f, 1.f, 1.f, 1.f);
            }
            const float4 g4 = ((const float4*)gam)[tid];
            const float4 b4 = ((const float4*)bet)[tid];
            float4 A, Bc;
            A.x = iv.x * g4.x; A.y = iv.y * g4.y;
            A.z = iv.z * g4.z; A.w = iv.w * g4.w;
            Bc.x = b4.x - m.x * A.x; Bc.y = b4.y - m.y * A.y;
            Bc.z = b4.z - m.z * A.z; Bc.w = b4.w - m.w * A.w;
            pS[0][tid] = A; pQ[0][tid] = Bc;   // same-wave lanes only
        }
        __syncthreads();
        A_out = pS[0][dg]; Bc_out = pQ[0][dg];
    };

    float4 cache[RV];
    float4 s, q, A0, Bc0, A1, Bc1;

    // ---------------- phase A0: load node chunk -> regs, accumulate --------
    s = make_float4(0.f, 0.f, 0.f, 0.f);
    q = make_float4(0.f, 0.f, 0.f, 0.f);
    if (cnt0 > 0) {
        const int hi0 = fc0 - 1;
        #pragma unroll
        for (int k = 0; k < RV; ++k) {
            const int idx = k * 256 + tid;
            cache[k] = xn[fb0 + (size_t)min(idx, hi0)];
        }
        #pragma unroll
        for (int k = 0; k < RV; ++k) {
            const int idx = k * 256 + tid;
            float4 v = cache[k];
            if (idx >= fc0) v = make_float4(0.f, 0.f, 0.f, 0.f);
            acc4(s, q, v);
        }
        for (int j = CAP + tid; j < fc0; j += 256)
            acc4(s, q, xn[fb0 + j]);
    }
    fold(s, q, cnt0, gn, bn, A0, Bc0);

    // ------ mid: store node (regs) INTERLEAVED with load edge -> same regs -
    s = make_float4(0.f, 0.f, 0.f, 0.f);
    q = make_float4(0.f, 0.f, 0.f, 0.f);
    {
        const int hi1 = (cnt1 > 0) ? (fc1 - 1) : 0;
        #pragma unroll
        for (int k = 0; k < RV; ++k) {
            const int idx = k * 256 + tid;
            if (cnt0 > 0 && idx < fc0)
                nt_store4(&on[fb0 + idx], affine4(cache[k], A0, Bc0));
            if (cnt1 > 0)
                cache[k] = xe[fb1 + (size_t)min(idx, hi1)];
        }
        // node tail write (re-read just-streamed rows: L2-hot)
        if (cnt0 > 0)
            for (int j = CAP + tid; j < fc0; j += 256)
                nt_store4(&on[fb0 + j], affine4(xn[fb0 + j], A0, Bc0));
        // edge accumulate from regs + tail stream
        if (cnt1 > 0) {
            #pragma unroll
            for (int k = 0; k < RV; ++k) {
                const int idx = k * 256 + tid;
                float4 v = cache[k];
                if (idx >= fc1) v = make_float4(0.f, 0.f, 0.f, 0.f);
                acc4(s, q, v);
            }
            for (int j = CAP + tid; j < fc1; j += 256)
                acc4(s, q, xe[fb1 + j]);
        }
    }
    fold(s, q, cnt1, ge, be, A1, Bc1);

    // ---------------- phase B1: store edge from regs -----------------------
    if (cnt1 > 0) {
        #pragma unroll
        for (int k = 0; k < RV; ++k) {
            const int idx = k * 256 + tid;
            if (idx < fc1)
                nt_store4(&oe[fb1 + idx], affine4(cache[k], A1, Bc1));
        }
        for (int j = CAP + tid; j < fc1; j += 256)
            nt_store4(&oe[fb1 + j], affine4(xe[fb1 + j], A1, Bc1));
    }
}

extern "C" void kernel_launch(void* const* d_in, const int* in_sizes, int n_in,
                              void* d_out, int out_size, void* d_ws, size_t ws_size,
                              hipStream_t stream) {
    const float* node_feat  = (const float*)d_in[0];
    const float* edge_feat  = (const float*)d_in[1];
    const float* node_gamma = (const float*)d_in[2];
    const float* node_beta  = (const float*)d_in[3];
    const float* edge_gamma = (const float*)d_in[4];
    const float* edge_beta  = (const float*)d_in[5];
    const int*   node_seg   = (const int*)d_in[6];
    const int*   edge_seg   = (const int*)d_in[7];

    const int D = in_sizes[2];        // 128
    const int N = in_sizes[0] / D;    // 1,000,000
    const int B = 1024;               // num_graphs (fixed by setup_inputs)

    float* out_node = (float*)d_out;
    float* out_edge = out_node + (size_t)N * (size_t)D;

    seg_norm_rr<<<dim3((unsigned)B), 256, 0, stream>>>(
        (const float4*)node_feat, (const float4*)edge_feat,
        node_gamma, node_beta, edge_gamma, edge_beta,
        node_seg, edge_seg,
        (float4*)out_node, (float4*)out_edge, N);
}